// Round 1
// baseline (199.176 us; speedup 1.0000x reference)
//
#include <hip/hip_runtime.h>

#define DT 0.1f
#define D 256

// One wave (64 lanes) per agent row. Lane l owns elements e0 = 4*l .. 4*l+3
// of every 256-wide row. Weights are loaded once per wave into registers
// (grid-stride loop amortizes), rows are gathered/scattered as coalesced
// float4 accesses (1 KB per row per wave).
template <bool UNI>
__global__ __launch_bounds__(256) void agent_step_kernel(
    const float* __restrict__ x,
    const float* __restrict__ tgt,
    const int* __restrict__ idx,
    int n,
    const float* __restrict__ Wproj, const float* __restrict__ bproj,
    const float* __restrict__ Wf2s,  const float* __restrict__ bf2s,
    const float* __restrict__ Ws2f,  const float* __restrict__ bs2f,
    float* __restrict__ out)
{
    const int lane = threadIdx.x & 63;
    const int gwave = (blockIdx.x * blockDim.x + threadIdx.x) >> 6;
    const int nwave = (gridDim.x * blockDim.x) >> 6;
    const int e0 = lane << 2;

    // --- per-lane weight slices (held in VGPRs across the agent loop) ---
    // W_f2s is (256,4) row-major: rows e0..e0+3, each 4 floats.
    const float4 wf0 = *(const float4*)(Wf2s + (e0 + 0) * 4);
    const float4 wf1 = *(const float4*)(Wf2s + (e0 + 1) * 4);
    const float4 wf2 = *(const float4*)(Wf2s + (e0 + 2) * 4);
    const float4 wf3 = *(const float4*)(Wf2s + (e0 + 3) * 4);
    // W_proj is (256,2): rows e0..e0+3 -> 8 contiguous floats.
    const float4 wp01 = *(const float4*)(Wproj + (e0 + 0) * 2); // rows e0 (x,y), e0+1 (z,w)
    const float4 wp23 = *(const float4*)(Wproj + (e0 + 2) * 2); // rows e0+2, e0+3
    // W_s2f is (4,256): column slice j = e0..e0+3 of each of the 4 rows.
    const float4 ws0 = *(const float4*)(Ws2f + 0 * D + e0);
    const float4 ws1 = *(const float4*)(Ws2f + 1 * D + e0);
    const float4 ws2 = *(const float4*)(Ws2f + 2 * D + e0);
    const float4 ws3 = *(const float4*)(Ws2f + 3 * D + e0);
    const float4 bs  = *(const float4*)(bs2f + e0);
    const float bf0 = bf2s[0], bf1 = bf2s[1], bf2v = bf2s[2], bf3 = bf2s[3];
    const float bp0 = bproj[0], bp1 = bproj[1];

    for (int t = gwave; t < n; t += nwave) {
        const int row = idx[t];
        const size_t base = (size_t)row * D + e0;
        const float4 tg = *(const float4*)(tgt + base);
        const float4 xv = *(const float4*)(x + base);

        // partial dot products (per-lane contribution to the 6 reduced scalars)
        float s0 = tg.x * wf0.x + tg.y * wf1.x + tg.z * wf2.x + tg.w * wf3.x;
        float s1 = tg.x * wf0.y + tg.y * wf1.y + tg.z * wf2.y + tg.w * wf3.y;
        float s2 = tg.x * wf0.z + tg.y * wf1.z + tg.z * wf2.z + tg.w * wf3.z;
        float s3 = tg.x * wf0.w + tg.y * wf1.w + tg.z * wf2.w + tg.w * wf3.w;
        float u0 = xv.x * wp01.x + xv.y * wp01.z + xv.z * wp23.x + xv.w * wp23.z;
        float u1 = xv.x * wp01.y + xv.y * wp01.w + xv.z * wp23.y + xv.w * wp23.w;

        // butterfly all-reduce across the 64-lane wave
        #pragma unroll
        for (int m = 1; m < 64; m <<= 1) {
            s0 += __shfl_xor(s0, m);
            s1 += __shfl_xor(s1, m);
            s2 += __shfl_xor(s2, m);
            s3 += __shfl_xor(s3, m);
            u0 += __shfl_xor(u0, m);
            u1 += __shfl_xor(u1, m);
        }
        s0 += bf0; s1 += bf1; s2 += bf2v; s3 += bf3;
        u0 += bp0; u1 += bp1;

        // dynamics step (all lanes hold identical s/u; computed redundantly)
        if (UNI) {
            const float th = s2, v = s3;
            s0 += DT * v * __cosf(th);
            s1 += DT * v * __sinf(th);
            s2 += DT * u1;   // deriv col2 = u[:,1]
            s3 += DT * u0;   // deriv col3 = u[:,0]
        } else {
            s0 += DT * s2;
            s1 += DT * s3;
            s2 += DT * u0;
            s3 += DT * u1;
        }

        // feat = s @ W_s2f + b_s2f  (lane emits its 4 output columns)
        float4 o;
        o.x = bs.x + s0 * ws0.x + s1 * ws1.x + s2 * ws2.x + s3 * ws3.x;
        o.y = bs.y + s0 * ws0.y + s1 * ws1.y + s2 * ws2.y + s3 * ws3.y;
        o.z = bs.z + s0 * ws0.z + s1 * ws1.z + s2 * ws2.z + s3 * ws3.z;
        o.w = bs.w + s0 * ws0.w + s1 * ws1.w + s2 * ws2.w + s3 * ws3.w;
        *(float4*)(out + base) = o;
    }
}

extern "C" void kernel_launch(void* const* d_in, const int* in_sizes, int n_in,
                              void* d_out, int out_size, void* d_ws, size_t ws_size,
                              hipStream_t stream) {
    const float* x        = (const float*)d_in[0];
    const float* tgt      = (const float*)d_in[1];
    const int*   idx_a    = (const int*)d_in[2];
    const int*   idx_b    = (const int*)d_in[3];
    const float* W_proj_a = (const float*)d_in[4];
    const float* b_proj_a = (const float*)d_in[5];
    const float* W_proj_b = (const float*)d_in[6];
    const float* b_proj_b = (const float*)d_in[7];
    const float* W_f2s_a  = (const float*)d_in[8];
    const float* b_f2s_a  = (const float*)d_in[9];
    const float* W_f2s_b  = (const float*)d_in[10];
    const float* b_f2s_b  = (const float*)d_in[11];
    const float* W_s2f_a  = (const float*)d_in[12];
    const float* b_s2f_a  = (const float*)d_in[13];
    const float* W_s2f_b  = (const float*)d_in[14];
    const float* b_s2f_b  = (const float*)d_in[15];
    float* out = (float*)d_out;

    const int n_a = in_sizes[2];
    const int n_b = in_sizes[3];

    dim3 blk(256);
    // 4 waves/block; grid-stride loop over agents (2048 blocks = 8192 waves).
    int blocks_a = (n_a + 3) / 4; if (blocks_a > 2048) blocks_a = 2048;
    int blocks_b = (n_b + 3) / 4; if (blocks_b > 2048) blocks_b = 2048;

    if (n_a > 0)
        agent_step_kernel<false><<<blocks_a, blk, 0, stream>>>(
            x, tgt, idx_a, n_a, W_proj_a, b_proj_a, W_f2s_a, b_f2s_a,
            W_s2f_a, b_s2f_a, out);
    if (n_b > 0)
        agent_step_kernel<true><<<blocks_b, blk, 0, stream>>>(
            x, tgt, idx_b, n_b, W_proj_b, b_proj_b, W_f2s_b, b_f2s_b,
            W_s2f_b, b_s2f_b, out);
}

// Round 2
// 154.074 us; speedup vs baseline: 1.2927x; 1.2927x over previous
//
#include <hip/hip_runtime.h>
#include <stdint.h>

#define DT 0.1f
#define D 256

typedef float f32x4 __attribute__((ext_vector_type(4)));

// --------------------------------------------------------------------------
// Pass 1: invert the permutation into a per-row label (0 = group a / double
// integrator, 1 = group b / unicycle). idx_a ∪ idx_b covers every row exactly
// once, so every label element is written each call (ws poison is harmless).
// --------------------------------------------------------------------------
__global__ __launch_bounds__(256) void label_kernel(
    const int* __restrict__ idx_a, int n_a,
    const int* __restrict__ idx_b, int n_b,
    uint8_t* __restrict__ label)
{
    int tid = blockIdx.x * blockDim.x + threadIdx.x;
    if (tid < n_a) {
        label[idx_a[tid]] = 0;
    } else if (tid - n_a < n_b) {
        label[idx_b[tid - n_a]] = 1;
    }
}

// Per-lane register slice of one weight set. Lane l owns output/input
// elements e0 = 4l .. 4l+3 of every 256-wide row.
struct WsetRegs {
    f32x4 wf0, wf1, wf2, wf3;   // W_f2s (256,4) rows e0..e0+3
    f32x4 wp01, wp23;           // W_proj (256,2) rows e0..e0+3 (packed pairs)
    f32x4 ws0, ws1, ws2, ws3;   // W_s2f (4,256) column slice e0..e0+3
    f32x4 bs;                   // b_s2f slice
    float bf0, bf1, bf2, bf3;   // b_f2s (uniform -> SGPRs)
    float bp0, bp1;             // b_proj (uniform -> SGPRs)
};

__device__ inline WsetRegs load_wset(int e0,
    const float* __restrict__ Wproj, const float* __restrict__ bproj,
    const float* __restrict__ Wf2s,  const float* __restrict__ bf2s,
    const float* __restrict__ Ws2f,  const float* __restrict__ bs2f)
{
    WsetRegs w;
    w.wf0  = *(const f32x4*)(Wf2s + (e0 + 0) * 4);
    w.wf1  = *(const f32x4*)(Wf2s + (e0 + 1) * 4);
    w.wf2  = *(const f32x4*)(Wf2s + (e0 + 2) * 4);
    w.wf3  = *(const f32x4*)(Wf2s + (e0 + 3) * 4);
    w.wp01 = *(const f32x4*)(Wproj + (e0 + 0) * 2);
    w.wp23 = *(const f32x4*)(Wproj + (e0 + 2) * 2);
    w.ws0  = *(const f32x4*)(Ws2f + 0 * D + e0);
    w.ws1  = *(const f32x4*)(Ws2f + 1 * D + e0);
    w.ws2  = *(const f32x4*)(Ws2f + 2 * D + e0);
    w.ws3  = *(const f32x4*)(Ws2f + 3 * D + e0);
    w.bs   = *(const f32x4*)(bs2f + e0);
    w.bf0 = bf2s[0]; w.bf1 = bf2s[1]; w.bf2 = bf2s[2]; w.bf3 = bf2s[3];
    w.bp0 = bproj[0]; w.bp1 = bproj[1];
    return w;
}

__device__ inline void reduce6(float& s0, float& s1, float& s2, float& s3,
                               float& u0, float& u1)
{
    #pragma unroll
    for (int m = 1; m < 64; m <<= 1) {
        s0 += __shfl_xor(s0, m);
        s1 += __shfl_xor(s1, m);
        s2 += __shfl_xor(s2, m);
        s3 += __shfl_xor(s3, m);
        u0 += __shfl_xor(u0, m);
        u1 += __shfl_xor(u1, m);
    }
}

template <bool UNI>
__device__ inline f32x4 compute_row(const f32x4 tg, const f32x4 xv,
                                    const WsetRegs& w)
{
    float s0 = tg.x * w.wf0.x + tg.y * w.wf1.x + tg.z * w.wf2.x + tg.w * w.wf3.x;
    float s1 = tg.x * w.wf0.y + tg.y * w.wf1.y + tg.z * w.wf2.y + tg.w * w.wf3.y;
    float s2 = tg.x * w.wf0.z + tg.y * w.wf1.z + tg.z * w.wf2.z + tg.w * w.wf3.z;
    float s3 = tg.x * w.wf0.w + tg.y * w.wf1.w + tg.z * w.wf2.w + tg.w * w.wf3.w;
    float u0 = xv.x * w.wp01.x + xv.y * w.wp01.z + xv.z * w.wp23.x + xv.w * w.wp23.z;
    float u1 = xv.x * w.wp01.y + xv.y * w.wp01.w + xv.z * w.wp23.y + xv.w * w.wp23.w;

    reduce6(s0, s1, s2, s3, u0, u1);

    s0 += w.bf0; s1 += w.bf1; s2 += w.bf2; s3 += w.bf3;
    u0 += w.bp0; u1 += w.bp1;

    if (UNI) {
        const float th = s2, v = s3;
        s0 += DT * v * __cosf(th);
        s1 += DT * v * __sinf(th);
        s2 += DT * u1;
        s3 += DT * u0;
    } else {
        s0 += DT * s2;
        s1 += DT * s3;
        s2 += DT * u0;
        s3 += DT * u1;
    }

    f32x4 o;
    o.x = w.bs.x + s0 * w.ws0.x + s1 * w.ws1.x + s2 * w.ws2.x + s3 * w.ws3.x;
    o.y = w.bs.y + s0 * w.ws0.y + s1 * w.ws1.y + s2 * w.ws2.y + s3 * w.ws3.y;
    o.z = w.bs.z + s0 * w.ws0.z + s1 * w.ws1.z + s2 * w.ws2.z + s3 * w.ws3.z;
    o.w = w.bs.w + s0 * w.ws0.w + s1 * w.ws1.w + s2 * w.ws2.w + s3 * w.ws3.w;
    return o;
}

// --------------------------------------------------------------------------
// Pass 2: pure streaming. Wave w handles row w (+ grid stride): sequential
// coalesced reads of x/tgt, sequential write of out. Wave-uniform branch on
// label picks the weight set + dynamics. Nontemporal on the three 256 MB
// read-once/write-once streams.
// --------------------------------------------------------------------------
__global__ __launch_bounds__(256) void fused_stream_kernel(
    const float* __restrict__ x,
    const float* __restrict__ tgt,
    const uint8_t* __restrict__ label,
    float* __restrict__ out,
    int n,
    const float* __restrict__ Wproj_a, const float* __restrict__ bproj_a,
    const float* __restrict__ Wf2s_a,  const float* __restrict__ bf2s_a,
    const float* __restrict__ Ws2f_a,  const float* __restrict__ bs2f_a,
    const float* __restrict__ Wproj_b, const float* __restrict__ bproj_b,
    const float* __restrict__ Wf2s_b,  const float* __restrict__ bf2s_b,
    const float* __restrict__ Ws2f_b,  const float* __restrict__ bs2f_b)
{
    const int lane  = threadIdx.x & 63;
    const int gwave = (blockIdx.x * blockDim.x + threadIdx.x) >> 6;
    const int nwave = (gridDim.x * blockDim.x) >> 6;
    const int e0 = lane << 2;

    const WsetRegs wa = load_wset(e0, Wproj_a, bproj_a, Wf2s_a, bf2s_a, Ws2f_a, bs2f_a);
    const WsetRegs wb = load_wset(e0, Wproj_b, bproj_b, Wf2s_b, bf2s_b, Ws2f_b, bs2f_b);

    for (int row = gwave; row < n; row += nwave) {
        const size_t base = (size_t)row * D + e0;
        const f32x4 tg = __builtin_nontemporal_load((const f32x4*)(tgt + base));
        const f32x4 xv = __builtin_nontemporal_load((const f32x4*)(x + base));
        const int lab = label[row];

        f32x4 o;
        if (lab == 0) {
            o = compute_row<false>(tg, xv, wa);
        } else {
            o = compute_row<true>(tg, xv, wb);
        }
        __builtin_nontemporal_store(o, (f32x4*)(out + base));
    }
}

extern "C" void kernel_launch(void* const* d_in, const int* in_sizes, int n_in,
                              void* d_out, int out_size, void* d_ws, size_t ws_size,
                              hipStream_t stream) {
    const float* x        = (const float*)d_in[0];
    const float* tgt      = (const float*)d_in[1];
    const int*   idx_a    = (const int*)d_in[2];
    const int*   idx_b    = (const int*)d_in[3];
    const float* W_proj_a = (const float*)d_in[4];
    const float* b_proj_a = (const float*)d_in[5];
    const float* W_proj_b = (const float*)d_in[6];
    const float* b_proj_b = (const float*)d_in[7];
    const float* W_f2s_a  = (const float*)d_in[8];
    const float* b_f2s_a  = (const float*)d_in[9];
    const float* W_f2s_b  = (const float*)d_in[10];
    const float* b_f2s_b  = (const float*)d_in[11];
    const float* W_s2f_a  = (const float*)d_in[12];
    const float* b_s2f_a  = (const float*)d_in[13];
    const float* W_s2f_b  = (const float*)d_in[14];
    const float* b_s2f_b  = (const float*)d_in[15];
    float* out = (float*)d_out;

    const int n_a = in_sizes[2];
    const int n_b = in_sizes[3];
    const int n   = n_a + n_b;            // = N_AGENT (permutation covers all rows)

    uint8_t* label = (uint8_t*)d_ws;      // needs n bytes; ws is MB-scale scratch

    {
        int total = n;
        int blocks = (total + 255) / 256;
        label_kernel<<<blocks, 256, 0, stream>>>(idx_a, n_a, idx_b, n_b, label);
    }
    {
        // 4 waves/block; 2048 blocks = 8192 waves -> 32 sequential rows/wave.
        int blocks = (n + 3) / 4;
        if (blocks > 2048) blocks = 2048;
        fused_stream_kernel<<<blocks, 256, 0, stream>>>(
            x, tgt, label, out, n,
            W_proj_a, b_proj_a, W_f2s_a, b_f2s_a, W_s2f_a, b_s2f_a,
            W_proj_b, b_proj_b, W_f2s_b, b_f2s_b, W_s2f_b, b_s2f_b);
    }
}